// Round 8
// baseline (343.611 us; speedup 1.0000x reference)
//
#include <hip/hip_runtime.h>

#define DIM 64
#define CHUNK 8192      // edges per partition block
#define MAXNB 512       // max coarse buckets (N <= 524288 with BSHIFT=10)
#define BSHIFT 10
#define RPB 1024        // rows per bucket (1 << BSHIFT)
#define PADMASK 7       // rows padded to multiple of 8
#define CONVB 1024      // conv blocks appended to p1a grid

typedef int   iv2 __attribute__((ext_vector_type(2)));
typedef int   iv4 __attribute__((ext_vector_type(4)));
typedef float fv4 __attribute__((ext_vector_type(4)));
#define NTL(p) __builtin_nontemporal_load(p)

__device__ __forceinline__ unsigned short f2bf(float f) {
    unsigned int u = __float_as_uint(f);
    return (unsigned short)((u + 0x7FFFu + ((u >> 16) & 1u)) >> 16);  // RNE
}
__device__ __forceinline__ float4 bf2f4(uint2 g) {
    float4 x;
    x.x = __uint_as_float(g.x << 16);
    x.y = __uint_as_float(g.x & 0xffff0000u);
    x.z = __uint_as_float(g.y << 16);
    x.w = __uint_as_float(g.y & 0xffff0000u);
    return x;
}

// inclusive block scan over 256 per-thread values; sh[255] = total after call
__device__ __forceinline__ int blockScan256(int v, int* sh) {
    int t = threadIdx.x;
    sh[t] = v;
    __syncthreads();
    for (int off = 1; off < 256; off <<= 1) {
        int x = (t >= off) ? sh[t - off] : 0;
        __syncthreads();
        sh[t] += x;
        __syncthreads();
    }
    return sh[t];
}

// ---------------- P1a (coarse hist) + optional fused f32->bf16 conv ----------------
// Blocks [0,NBLK): LDS histogram of row>>BSHIFT. Blocks [NBLK,NBLK+nConv): bf16 pack.

__global__ void p1a_conv(const int* __restrict__ row, int E, int NB,
                         int* __restrict__ counts,
                         const float* __restrict__ u, const float* __restrict__ it,
                         int nu, int ntot, unsigned short* __restrict__ o, int NBLK) {
    __shared__ int h[MAXNB];
    int blk = blockIdx.x;
    if (blk < NBLK) {
        for (int b = threadIdx.x; b < NB; b += 256) h[b] = 0;
        __syncthreads();
        int base = blk * CHUNK;
        int end = min(base + CHUNK, E);
        int vend = base + ((end - base) & ~3);
        for (int i = base + threadIdx.x * 4; i < vend; i += 1024) {
            iv4 r = NTL((const iv4*)(row + i));
            atomicAdd(&h[r.x >> BSHIFT], 1);
            atomicAdd(&h[r.y >> BSHIFT], 1);
            atomicAdd(&h[r.z >> BSHIFT], 1);
            atomicAdd(&h[r.w >> BSHIFT], 1);
        }
        for (int i = vend + threadIdx.x; i < end; i += 256) atomicAdd(&h[row[i] >> BSHIFT], 1);
        __syncthreads();
        for (int b = threadIdx.x; b < NB; b += 256) counts[(size_t)blk * NB + b] = h[b];
    } else {
        int i = (blk - NBLK) * 256 + threadIdx.x;
        int stride = CONVB * 256;
        int n8 = ntot >> 3;
        for (int t = i; t < n8; t += stride) {
            int e = t * 8;
            const float* src = (e < nu) ? (u + e) : (it + (e - nu));
            fv4 x = NTL((const fv4*)src);
            fv4 y = NTL((const fv4*)(src + 4));
            uint4 v;
            v.x = (unsigned)f2bf(x.x) | ((unsigned)f2bf(x.y) << 16);
            v.y = (unsigned)f2bf(x.z) | ((unsigned)f2bf(x.w) << 16);
            v.z = (unsigned)f2bf(y.x) | ((unsigned)f2bf(y.y) << 16);
            v.w = (unsigned)f2bf(y.z) | ((unsigned)f2bf(y.w) << 16);
            ((uint4*)o)[t] = v;
        }
    }
}

__global__ void p1b_scan(int* __restrict__ counts, int NBLK, int NB,
                         int* __restrict__ bucketTotal) {
    int b = blockIdx.x, t = threadIdx.x;
    __shared__ int sh[256];
    int v[8];
    int run = 0;
#pragma unroll
    for (int i = 0; i < 8; i++) {
        int idx = t * 8 + i;
        int c = (idx < NBLK) ? counts[(size_t)idx * NB + b] : 0;
        v[i] = run;  // exclusive within thread
        run += c;
    }
    int inc = blockScan256(run, sh);
    int excl = inc - run;
#pragma unroll
    for (int i = 0; i < 8; i++) {
        int idx = t * 8 + i;
        if (idx < NBLK) counts[(size_t)idx * NB + b] = v[i] + excl;
    }
    if (t == 255) bucketTotal[b] = sh[255];
}

__global__ void p_scan_tot(const int* __restrict__ bucketTotal, int NB,
                           int* __restrict__ bucketStart) {
    int t = threadIdx.x;
    __shared__ int sh[256];
    int v[8];
    int run = 0;
#pragma unroll
    for (int i = 0; i < 8; i++) {
        int idx = t * 8 + i;
        int c = (idx < NB) ? bucketTotal[idx] : 0;
        v[i] = run;
        run += c;
    }
    int inc = blockScan256(run, sh);
    int excl = inc - run;
#pragma unroll
    for (int i = 0; i < 8; i++) {
        int idx = t * 8 + i;
        if (idx < NB) bucketStart[idx] = v[i] + excl;
    }
    if (t == 255) bucketStart[NB] = sh[255];
}

__global__ void p1c_scatter(const int* __restrict__ row, const int* __restrict__ col,
                            const float* __restrict__ vals, int E, int NB,
                            const int* __restrict__ counts, const int* __restrict__ bucketStart,
                            int2* __restrict__ bdata) {
    __shared__ int cur[MAXNB];
    int blk = blockIdx.x;
    for (int b = threadIdx.x; b < NB; b += 256)
        cur[b] = bucketStart[b] + counts[(size_t)blk * NB + b];
    __syncthreads();
    int base = blk * CHUNK;
    int end = min(base + CHUNK, E);
    int vend = base + ((end - base) & ~3);
    for (int i = base + threadIdx.x * 4; i < vend; i += 1024) {
        iv4 r = NTL((const iv4*)(row + i));
        iv4 c = NTL((const iv4*)(col + i));
        fv4 v = NTL((const fv4*)(vals + i));
        int p0 = atomicAdd(&cur[r.x >> BSHIFT], 1);
        int p1 = atomicAdd(&cur[r.y >> BSHIFT], 1);
        int p2 = atomicAdd(&cur[r.z >> BSHIFT], 1);
        int p3 = atomicAdd(&cur[r.w >> BSHIFT], 1);
        bdata[p0] = make_int2(((r.x & (RPB - 1)) << 20) | c.x, __float_as_int(v.x));
        bdata[p1] = make_int2(((r.y & (RPB - 1)) << 20) | c.y, __float_as_int(v.y));
        bdata[p2] = make_int2(((r.z & (RPB - 1)) << 20) | c.z, __float_as_int(v.z));
        bdata[p3] = make_int2(((r.w & (RPB - 1)) << 20) | c.w, __float_as_int(v.w));
    }
    for (int i = vend + threadIdx.x; i < end; i += 256) {
        int r = row[i];
        int p = atomicAdd(&cur[r >> BSHIFT], 1);
        bdata[p] = make_int2(((r & (RPB - 1)) << 20) | col[i], __float_as_int(vals[i]));
    }
}

// P2: per-bucket regroup by exact row into PADDED rows (pads = colOff 0, val 0).
// pairs.x stores col*128 (byte offset). Pass 1 warms L2; pass 2 NT (last read).
__global__ void p2_group(const int2* __restrict__ bdata, const int* __restrict__ bucketStart,
                         int NB, int N, int padSlop,
                         int* __restrict__ rowStart, int* __restrict__ rowLen,
                         int2* __restrict__ pairs) {
    __shared__ int hist[RPB];
    __shared__ int sh[256];
    __shared__ int cur[RPB];
    int b = blockIdx.x, t = threadIdx.x;
    int s0 = bucketStart[b], s1 = bucketStart[b + 1];
    int pbase = s0 + b * padSlop;
    for (int i = t; i < RPB; i += 256) hist[i] = 0;
    __syncthreads();
    for (int i = s0 + t; i < s1; i += 256)
        atomicAdd(&hist[(bdata[i].x >> 20) & (RPB - 1)], 1);
    __syncthreads();
    int v[4];
    int run = 0;
#pragma unroll
    for (int i = 0; i < 4; i++) {
        int h = hist[t * 4 + i];
        int hp = (h + PADMASK) & ~PADMASK;
        v[i] = run;  // exclusive within thread
        run += hp;
    }
    int inc = blockScan256(run, sh);
    int excl = inc - run;
#pragma unroll
    for (int i = 0; i < 4; i++) {
        int r = (b << BSHIFT) + t * 4 + i;
        int st = excl + v[i];
        if (r < N) {
            int h = hist[t * 4 + i];
            rowStart[r] = pbase + st;
            rowLen[r] = (h + PADMASK) & ~PADMASK;
        }
        cur[t * 4 + i] = st;
    }
    __syncthreads();
    // scatter real edges into row-grouped slots (bdata window is L2-hot from pass 1)
    for (int i = s0 + t; i < s1; i += 256) {
        iv2 e = NTL((const iv2*)(bdata + i));
        int rl = (e.x >> 20) & (RPB - 1);
        int pos = atomicAdd(&cur[rl], 1);
        pairs[pbase + pos] = make_int2((e.x & 0xFFFFF) << 7, e.y);
    }
    __syncthreads();
    // fill ONLY the pad slots (colOff=0 -> row 0, val=0)
#pragma unroll
    for (int i = 0; i < 4; i++) {
        int h = hist[t * 4 + i];
        int hp = (h + PADMASK) & ~PADMASK;
        int st = excl + v[i];
        for (int p = st + h; p < st + hp; p++)
            pairs[pbase + p] = make_int2(0, 0);
    }
}

// ---------------- layer-1 SpMM: wave per row, 4-deep gather pipeline ----------------
// Pair metadata streams via NT loads (read once) so L2 keeps the emb16 gather set.

__global__ void spmm1_k(const unsigned short* __restrict__ emb16,
                        const int* __restrict__ rowStart, const int* __restrict__ rowLen,
                        const int2* __restrict__ pairs,
                        int n_total, unsigned short* __restrict__ e1) {
    int wave = (blockIdx.x * blockDim.x + threadIdx.x) >> 6;
    int lane = threadIdx.x & 63;
    if (wave >= n_total) return;
    int eg = lane >> 4, dp = lane & 15;
    unsigned off0 = dp * 8u;
    const char* base = (const char*)emb16;
    int len = NTL(rowLen + wave);
    const int2* pp = pairs + NTL(rowStart + wave);
    float4 a0 = {0.f, 0.f, 0.f, 0.f}, a1 = {0.f, 0.f, 0.f, 0.f};
    float4 a2 = {0.f, 0.f, 0.f, 0.f}, a3 = {0.f, 0.f, 0.f, 0.f};
    int k = 0;
    for (; k + 16 <= len; k += 16) {
        iv4 q0 = NTL((const iv4*)(pp + k + 2 * eg));      // edges 2eg, 2eg+1
        iv4 q1 = NTL((const iv4*)(pp + k + 8 + 2 * eg));  // edges 8+2eg, 8+2eg+1
        uint2 g0 = *(const uint2*)(base + ((unsigned)q0.x + off0));
        uint2 g1 = *(const uint2*)(base + ((unsigned)q0.z + off0));
        uint2 g2 = *(const uint2*)(base + ((unsigned)q1.x + off0));
        uint2 g3 = *(const uint2*)(base + ((unsigned)q1.z + off0));
        float v0 = __int_as_float(q0.y), v1 = __int_as_float(q0.w);
        float v2 = __int_as_float(q1.y), v3 = __int_as_float(q1.w);
        float4 x0 = bf2f4(g0), x1 = bf2f4(g1), x2 = bf2f4(g2), x3 = bf2f4(g3);
        a0.x += v0 * x0.x; a0.y += v0 * x0.y; a0.z += v0 * x0.z; a0.w += v0 * x0.w;
        a1.x += v1 * x1.x; a1.y += v1 * x1.y; a1.z += v1 * x1.z; a1.w += v1 * x1.w;
        a2.x += v2 * x2.x; a2.y += v2 * x2.y; a2.z += v2 * x2.z; a2.w += v2 * x2.w;
        a3.x += v3 * x3.x; a3.y += v3 * x3.y; a3.z += v3 * x3.z; a3.w += v3 * x3.w;
    }
    for (; k < len; k += 8) {  // at most one trailing 8-block
        iv4 q0 = NTL((const iv4*)(pp + k + 2 * eg));
        uint2 g0 = *(const uint2*)(base + ((unsigned)q0.x + off0));
        uint2 g1 = *(const uint2*)(base + ((unsigned)q0.z + off0));
        float v0 = __int_as_float(q0.y), v1 = __int_as_float(q0.w);
        float4 x0 = bf2f4(g0), x1 = bf2f4(g1);
        a0.x += v0 * x0.x; a0.y += v0 * x0.y; a0.z += v0 * x0.z; a0.w += v0 * x0.w;
        a1.x += v1 * x1.x; a1.y += v1 * x1.y; a1.z += v1 * x1.z; a1.w += v1 * x1.w;
    }
    float4 s;
    s.x = (a0.x + a1.x) + (a2.x + a3.x);
    s.y = (a0.y + a1.y) + (a2.y + a3.y);
    s.z = (a0.z + a1.z) + (a2.z + a3.z);
    s.w = (a0.w + a1.w) + (a2.w + a3.w);
    s.x += __shfl_xor(s.x, 16); s.y += __shfl_xor(s.y, 16);
    s.z += __shfl_xor(s.z, 16); s.w += __shfl_xor(s.w, 16);
    s.x += __shfl_xor(s.x, 32); s.y += __shfl_xor(s.y, 32);
    s.z += __shfl_xor(s.z, 32); s.w += __shfl_xor(s.w, 32);
    if (eg == 0) {
        uint2 o;
        o.x = (unsigned)f2bf(s.x) | ((unsigned)f2bf(s.y) << 16);
        o.y = (unsigned)f2bf(s.z) | ((unsigned)f2bf(s.w) << 16);
        *(uint2*)(e1 + (size_t)wave * DIM + dp * 4) = o;
    }
}

// ---------------- fused layer-2 + gather + dot epilogue ----------------

__global__ void final_k(const float* __restrict__ emb_user, const float* __restrict__ emb_item,
                        int n_user, const unsigned short* __restrict__ e1,
                        const int* __restrict__ rowStart, const int* __restrict__ rowLen,
                        const int2* __restrict__ pairs,
                        const int* __restrict__ u_nodes, const int* __restrict__ p_nodes,
                        const int* __restrict__ n_nodes, int B, float* __restrict__ out) {
    int wave = (blockIdx.x * blockDim.x + threadIdx.x) >> 6;
    int lane = threadIdx.x & 63;
    if (wave >= B) return;
    int eg = lane >> 4, dp = lane & 15;
    unsigned off0 = dp * 8u;
    const char* base = (const char*)e1;
    int nid[3] = {u_nodes[wave], p_nodes[wave], n_nodes[wave]};
    float4 l[3];
#pragma unroll
    for (int j = 0; j < 3; j++) {
        int r = nid[j];
        const float* base0 = (r < n_user) ? (emb_user + (size_t)r * DIM)
                                          : (emb_item + (size_t)(r - n_user) * DIM);
        float4 acc = *(const float4*)(base0 + dp * 4);                       // layer0 f32
        float4 t1 = bf2f4(*(const uint2*)(e1 + (size_t)r * DIM + dp * 4));   // layer1
        acc.x += t1.x; acc.y += t1.y; acc.z += t1.z; acc.w += t1.w;
        int len = rowLen[r];
        const int2* pp = pairs + rowStart[r];
        float4 a0 = {0.f, 0.f, 0.f, 0.f}, a1 = {0.f, 0.f, 0.f, 0.f};
        float4 a2 = {0.f, 0.f, 0.f, 0.f}, a3 = {0.f, 0.f, 0.f, 0.f};
        int k = 0;
        for (; k + 16 <= len; k += 16) {
            iv4 q0 = NTL((const iv4*)(pp + k + 2 * eg));
            iv4 q1 = NTL((const iv4*)(pp + k + 8 + 2 * eg));
            uint2 g0 = *(const uint2*)(base + ((unsigned)q0.x + off0));
            uint2 g1 = *(const uint2*)(base + ((unsigned)q0.z + off0));
            uint2 g2 = *(const uint2*)(base + ((unsigned)q1.x + off0));
            uint2 g3 = *(const uint2*)(base + ((unsigned)q1.z + off0));
            float v0 = __int_as_float(q0.y), v1 = __int_as_float(q0.w);
            float v2 = __int_as_float(q1.y), v3 = __int_as_float(q1.w);
            float4 x0 = bf2f4(g0), x1 = bf2f4(g1), x2 = bf2f4(g2), x3 = bf2f4(g3);
            a0.x += v0 * x0.x; a0.y += v0 * x0.y; a0.z += v0 * x0.z; a0.w += v0 * x0.w;
            a1.x += v1 * x1.x; a1.y += v1 * x1.y; a1.z += v1 * x1.z; a1.w += v1 * x1.w;
            a2.x += v2 * x2.x; a2.y += v2 * x2.y; a2.z += v2 * x2.z; a2.w += v2 * x2.w;
            a3.x += v3 * x3.x; a3.y += v3 * x3.y; a3.z += v3 * x3.z; a3.w += v3 * x3.w;
        }
        for (; k < len; k += 8) {
            iv4 q0 = NTL((const iv4*)(pp + k + 2 * eg));
            uint2 g0 = *(const uint2*)(base + ((unsigned)q0.x + off0));
            uint2 g1 = *(const uint2*)(base + ((unsigned)q0.z + off0));
            float v0 = __int_as_float(q0.y), v1 = __int_as_float(q0.w);
            float4 x0 = bf2f4(g0), x1 = bf2f4(g1);
            a0.x += v0 * x0.x; a0.y += v0 * x0.y; a0.z += v0 * x0.z; a0.w += v0 * x0.w;
            a1.x += v1 * x1.x; a1.y += v1 * x1.y; a1.z += v1 * x1.z; a1.w += v1 * x1.w;
        }
        float4 s;
        s.x = (a0.x + a1.x) + (a2.x + a3.x);
        s.y = (a0.y + a1.y) + (a2.y + a3.y);
        s.z = (a0.z + a1.z) + (a2.z + a3.z);
        s.w = (a0.w + a1.w) + (a2.w + a3.w);
        s.x += __shfl_xor(s.x, 16); s.y += __shfl_xor(s.y, 16);
        s.z += __shfl_xor(s.z, 16); s.w += __shfl_xor(s.w, 16);
        s.x += __shfl_xor(s.x, 32); s.y += __shfl_xor(s.y, 32);
        s.z += __shfl_xor(s.z, 32); s.w += __shfl_xor(s.w, 32);
        l[j].x = (acc.x + s.x) * (1.0f / 3.0f);
        l[j].y = (acc.y + s.y) * (1.0f / 3.0f);
        l[j].z = (acc.z + s.z) * (1.0f / 3.0f);
        l[j].w = (acc.w + s.w) * (1.0f / 3.0f);
    }
    float ps = l[0].x * l[1].x + l[0].y * l[1].y + l[0].z * l[1].z + l[0].w * l[1].w;
    float ns = l[0].x * l[2].x + l[0].y * l[2].y + l[0].z * l[2].z + l[0].w * l[2].w;
    ps += __shfl_xor(ps, 1); ns += __shfl_xor(ns, 1);
    ps += __shfl_xor(ps, 2); ns += __shfl_xor(ns, 2);
    ps += __shfl_xor(ps, 4); ns += __shfl_xor(ns, 4);
    ps += __shfl_xor(ps, 8); ns += __shfl_xor(ns, 8);
    if (lane == 0) {
        out[wave] = ps;
        out[B + wave] = ns;
    }
}

// fallback standalone conv (only if ws too small for separate emb16 region)
__global__ void conv2_k(const float* __restrict__ u, const float* __restrict__ it,
                        int nu, int ntot, unsigned short* __restrict__ o) {
    int i = blockIdx.x * blockDim.x + threadIdx.x;
    int stride = gridDim.x * blockDim.x;
    int n8 = ntot >> 3;
    for (int t = i; t < n8; t += stride) {
        int e = t * 8;
        const float* src = (e < nu) ? (u + e) : (it + (e - nu));
        fv4 x = NTL((const fv4*)src);
        fv4 y = NTL((const fv4*)(src + 4));
        uint4 v;
        v.x = (unsigned)f2bf(x.x) | ((unsigned)f2bf(x.y) << 16);
        v.y = (unsigned)f2bf(x.z) | ((unsigned)f2bf(x.w) << 16);
        v.z = (unsigned)f2bf(y.x) | ((unsigned)f2bf(y.y) << 16);
        v.w = (unsigned)f2bf(y.z) | ((unsigned)f2bf(y.w) << 16);
        ((uint4*)o)[t] = v;
    }
}

extern "C" void kernel_launch(void* const* d_in, const int* in_sizes, int n_in,
                              void* d_out, int out_size, void* d_ws, size_t ws_size,
                              hipStream_t stream) {
    const float* emb_user = (const float*)d_in[0];
    const float* emb_item = (const float*)d_in[1];
    const float* gvals    = (const float*)d_in[2];
    const int*   grow     = (const int*)d_in[3];
    const int*   gcol     = (const int*)d_in[4];
    const int*   unodes   = (const int*)d_in[5];
    const int*   pnodes   = (const int*)d_in[6];
    const int*   nnodes   = (const int*)d_in[7];
    float* out = (float*)d_out;

    int n_user = in_sizes[0] / DIM;
    int n_item = in_sizes[1] / DIM;
    int N = n_user + n_item;
    int E = in_sizes[2];
    int B = in_sizes[5];
    int NB = (N + RPB - 1) >> BSHIFT;
    int NBLK = (E + CHUNK - 1) / CHUNK;
    int padSlop = RPB * PADMASK;

    auto align256 = [](size_t x) { return (x + 255) & ~(size_t)255; };
    size_t embBytes = (size_t)N * DIM * 2;
    size_t countsBytes = (size_t)NBLK * NB * 4;
    size_t bdataBytes = (size_t)E * 8;
    size_t regionABytes = countsBytes > embBytes ? countsBytes : embBytes;  // counts / e1
    size_t pairsBytes = ((size_t)E + (size_t)NB * padSlop) * 8;
    size_t fixedBytes = align256((size_t)N * 4) * 2 + align256((size_t)MAXNB * 4) +
                        align256((size_t)(MAXNB + 1) * 4) + align256(pairsBytes) +
                        align256(regionABytes);
    // preferred: emb16 separate (enables conv fused into p1a, before bdata is written)
    bool sepEmb = fixedBytes + align256(bdataBytes) + align256(embBytes) <= ws_size;

    char* ws = (char*)d_ws;
    size_t off = 0;
    auto alloc = [&](size_t bytes) -> void* {
        void* p = ws + off;
        off = (off + bytes + 255) & ~(size_t)255;
        return p;
    };
    int*  rowStart    = (int*)alloc((size_t)N * 4);
    int*  rowLen      = (int*)alloc((size_t)N * 4);
    int*  bucketTotal = (int*)alloc((size_t)MAXNB * 4);
    int*  bucketStart = (int*)alloc((size_t)(MAXNB + 1) * 4);
    int2* pairs       = (int2*)alloc(pairsBytes);
    int2* bdata;
    unsigned short* emb16;
    if (sepEmb) {
        bdata = (int2*)alloc(bdataBytes);
        emb16 = (unsigned short*)alloc(embBytes);
    } else {
        char* regionB = (char*)alloc(bdataBytes > embBytes ? bdataBytes : embBytes);
        bdata = (int2*)regionB;            // dead after p2
        emb16 = (unsigned short*)regionB;  // written after p2 (overlay)
    }
    char* regionA = (char*)alloc(regionABytes);
    int*            counts = (int*)regionA;  // dead after p1c
    unsigned short* e1     = (unsigned short*)regionA;
    (void)n_in; (void)out_size;

    int nConv = sepEmb ? CONVB : 0;
    p1a_conv<<<NBLK + nConv, 256, 0, stream>>>(grow, E, NB, counts,
                                               emb_user, emb_item, n_user * DIM, N * DIM,
                                               emb16, NBLK);
    p1b_scan<<<NB, 256, 0, stream>>>(counts, NBLK, NB, bucketTotal);
    p_scan_tot<<<1, 256, 0, stream>>>(bucketTotal, NB, bucketStart);
    p1c_scatter<<<NBLK, 256, 0, stream>>>(grow, gcol, gvals, E, NB, counts, bucketStart, bdata);
    p2_group<<<NB, 256, 0, stream>>>(bdata, bucketStart, NB, N, padSlop,
                                     rowStart, rowLen, pairs);
    if (!sepEmb)  // overlay layout: pack after bdata is dead
        conv2_k<<<2048, 256, 0, stream>>>(emb_user, emb_item, n_user * DIM, N * DIM, emb16);

    spmm1_k<<<(N + 3) / 4, 256, 0, stream>>>(emb16, rowStart, rowLen, pairs, N, e1);
    final_k<<<(B + 3) / 4, 256, 0, stream>>>(emb_user, emb_item, n_user, e1,
                                             rowStart, rowLen, pairs,
                                             unodes, pnodes, nnodes, B, out);
}

// Round 9
// 305.407 us; speedup vs baseline: 1.1251x; 1.1251x over previous
//
#include <hip/hip_runtime.h>

#define DIM 64
#define CHUNK 8192      // edges per partition block
#define MAXNB 512       // max coarse buckets (N <= 524288 with BSHIFT=10)
#define BSHIFT 10
#define RPB 1024        // rows per bucket (1 << BSHIFT)
#define PADMASK 7       // rows padded to multiple of 8

__device__ __forceinline__ unsigned short f2bf(float f) {
    unsigned int u = __float_as_uint(f);
    return (unsigned short)((u + 0x7FFFu + ((u >> 16) & 1u)) >> 16);  // RNE
}
__device__ __forceinline__ float4 bf2f4(unsigned int lo, unsigned int hi) {
    float4 x;
    x.x = __uint_as_float(lo << 16);
    x.y = __uint_as_float(lo & 0xffff0000u);
    x.z = __uint_as_float(hi << 16);
    x.w = __uint_as_float(hi & 0xffff0000u);
    return x;
}
__device__ __forceinline__ float4 bf2f4(uint2 g) { return bf2f4(g.x, g.y); }

// inclusive block scan over 256 per-thread values; sh[255] = total after call
__device__ __forceinline__ int blockScan256(int v, int* sh) {
    int t = threadIdx.x;
    sh[t] = v;
    __syncthreads();
    for (int off = 1; off < 256; off <<= 1) {
        int x = (t >= off) ? sh[t - off] : 0;
        __syncthreads();
        sh[t] += x;
        __syncthreads();
    }
    return sh[t];
}

// ---------------- f32 -> packed bf16 conversion (both tables, one launch) ----------------

__global__ void conv2_k(const float* __restrict__ u, const float* __restrict__ it,
                        int nu, int ntot, unsigned short* __restrict__ o) {
    int i = blockIdx.x * blockDim.x + threadIdx.x;
    int stride = gridDim.x * blockDim.x;
    int n8 = ntot >> 3;
    for (int t = i; t < n8; t += stride) {
        int e = t * 8;
        const float* src = (e < nu) ? (u + e) : (it + (e - nu));
        float4 x = *(const float4*)src;
        float4 y = *(const float4*)(src + 4);
        uint4 v;
        v.x = (unsigned)f2bf(x.x) | ((unsigned)f2bf(x.y) << 16);
        v.y = (unsigned)f2bf(x.z) | ((unsigned)f2bf(x.w) << 16);
        v.z = (unsigned)f2bf(y.x) | ((unsigned)f2bf(y.y) << 16);
        v.w = (unsigned)f2bf(y.z) | ((unsigned)f2bf(y.w) << 16);
        ((uint4*)o)[t] = v;
    }
}

// ---------------- two-level counting sort (no global atomics) ----------------

__global__ void p1a_hist(const int* __restrict__ row, int E, int NB,
                         int* __restrict__ counts) {
    __shared__ int h[MAXNB];
    for (int b = threadIdx.x; b < NB; b += 256) h[b] = 0;
    __syncthreads();
    int base = blockIdx.x * CHUNK;
    int end = min(base + CHUNK, E);
    int vend = base + ((end - base) & ~3);
    for (int i = base + threadIdx.x * 4; i < vend; i += 1024) {
        int4 r = *(const int4*)(row + i);
        atomicAdd(&h[r.x >> BSHIFT], 1);
        atomicAdd(&h[r.y >> BSHIFT], 1);
        atomicAdd(&h[r.z >> BSHIFT], 1);
        atomicAdd(&h[r.w >> BSHIFT], 1);
    }
    for (int i = vend + threadIdx.x; i < end; i += 256) atomicAdd(&h[row[i] >> BSHIFT], 1);
    __syncthreads();
    int blk = blockIdx.x;
    for (int b = threadIdx.x; b < NB; b += 256) counts[(size_t)blk * NB + b] = h[b];
}

__global__ void p1b_scan(int* __restrict__ counts, int NBLK, int NB,
                         int* __restrict__ bucketTotal) {
    int b = blockIdx.x, t = threadIdx.x;
    __shared__ int sh[256];
    int v[8];
    int run = 0;
#pragma unroll
    for (int i = 0; i < 8; i++) {
        int idx = t * 8 + i;
        int c = (idx < NBLK) ? counts[(size_t)idx * NB + b] : 0;
        v[i] = run;  // exclusive within thread
        run += c;
    }
    int inc = blockScan256(run, sh);
    int excl = inc - run;
#pragma unroll
    for (int i = 0; i < 8; i++) {
        int idx = t * 8 + i;
        if (idx < NBLK) counts[(size_t)idx * NB + b] = v[i] + excl;
    }
    if (t == 255) bucketTotal[b] = sh[255];
}

__global__ void p_scan_tot(const int* __restrict__ bucketTotal, int NB,
                           int* __restrict__ bucketStart) {
    int t = threadIdx.x;
    __shared__ int sh[256];
    int v[8];
    int run = 0;
#pragma unroll
    for (int i = 0; i < 8; i++) {
        int idx = t * 8 + i;
        int c = (idx < NB) ? bucketTotal[idx] : 0;
        v[i] = run;
        run += c;
    }
    int inc = blockScan256(run, sh);
    int excl = inc - run;
#pragma unroll
    for (int i = 0; i < 8; i++) {
        int idx = t * 8 + i;
        if (idx < NB) bucketStart[idx] = v[i] + excl;
    }
    if (t == 255) bucketStart[NB] = sh[255];
}

__global__ void p1c_scatter(const int* __restrict__ row, const int* __restrict__ col,
                            const float* __restrict__ vals, int E, int NB,
                            const int* __restrict__ counts, const int* __restrict__ bucketStart,
                            int2* __restrict__ bdata) {
    __shared__ int cur[MAXNB];
    int blk = blockIdx.x;
    for (int b = threadIdx.x; b < NB; b += 256)
        cur[b] = bucketStart[b] + counts[(size_t)blk * NB + b];
    __syncthreads();
    int base = blk * CHUNK;
    int end = min(base + CHUNK, E);
    int vend = base + ((end - base) & ~3);
    for (int i = base + threadIdx.x * 4; i < vend; i += 1024) {
        int4 r = *(const int4*)(row + i);
        int4 c = *(const int4*)(col + i);
        float4 v = *(const float4*)(vals + i);
        int p0 = atomicAdd(&cur[r.x >> BSHIFT], 1);
        int p1 = atomicAdd(&cur[r.y >> BSHIFT], 1);
        int p2 = atomicAdd(&cur[r.z >> BSHIFT], 1);
        int p3 = atomicAdd(&cur[r.w >> BSHIFT], 1);
        bdata[p0] = make_int2(((r.x & (RPB - 1)) << 20) | c.x, __float_as_int(v.x));
        bdata[p1] = make_int2(((r.y & (RPB - 1)) << 20) | c.y, __float_as_int(v.y));
        bdata[p2] = make_int2(((r.z & (RPB - 1)) << 20) | c.z, __float_as_int(v.z));
        bdata[p3] = make_int2(((r.w & (RPB - 1)) << 20) | c.w, __float_as_int(v.w));
    }
    for (int i = vend + threadIdx.x; i < end; i += 256) {
        int r = row[i];
        int p = atomicAdd(&cur[r >> BSHIFT], 1);
        bdata[p] = make_int2(((r & (RPB - 1)) << 20) | col[i], __float_as_int(vals[i]));
    }
}

// P2: per-bucket regroup by exact row into PADDED rows (pads = colOff 0, val 0).
// pairs.x stores col*128 (byte offset). Only pad slots are filled post-scatter.
__global__ void p2_group(const int2* __restrict__ bdata, const int* __restrict__ bucketStart,
                         int NB, int N, int padSlop,
                         int* __restrict__ rowStart, int* __restrict__ rowLen,
                         int2* __restrict__ pairs) {
    __shared__ int hist[RPB];
    __shared__ int sh[256];
    __shared__ int cur[RPB];
    int b = blockIdx.x, t = threadIdx.x;
    int s0 = bucketStart[b], s1 = bucketStart[b + 1];
    int pbase = s0 + b * padSlop;
    for (int i = t; i < RPB; i += 256) hist[i] = 0;
    __syncthreads();
    for (int i = s0 + t; i < s1; i += 256)
        atomicAdd(&hist[(bdata[i].x >> 20) & (RPB - 1)], 1);
    __syncthreads();
    int v[4];
    int run = 0;
#pragma unroll
    for (int i = 0; i < 4; i++) {
        int h = hist[t * 4 + i];
        int hp = (h + PADMASK) & ~PADMASK;
        v[i] = run;  // exclusive within thread
        run += hp;
    }
    int inc = blockScan256(run, sh);
    int excl = inc - run;
#pragma unroll
    for (int i = 0; i < 4; i++) {
        int r = (b << BSHIFT) + t * 4 + i;
        int st = excl + v[i];
        if (r < N) {
            int h = hist[t * 4 + i];
            rowStart[r] = pbase + st;
            rowLen[r] = (h + PADMASK) & ~PADMASK;
        }
        cur[t * 4 + i] = st;
    }
    __syncthreads();
    // scatter real edges into row-grouped slots
    for (int i = s0 + t; i < s1; i += 256) {
        int2 e = bdata[i];
        int rl = (e.x >> 20) & (RPB - 1);
        int pos = atomicAdd(&cur[rl], 1);
        pairs[pbase + pos] = make_int2((e.x & 0xFFFFF) << 7, e.y);
    }
    __syncthreads();
    // fill ONLY the pad slots (colOff=0 -> row 0, val=0)
#pragma unroll
    for (int i = 0; i < 4; i++) {
        int h = hist[t * 4 + i];
        int hp = (h + PADMASK) & ~PADMASK;
        int st = excl + v[i];
        for (int p = st + h; p < st + hp; p++)
            pairs[pbase + p] = make_int2(0, 0);
    }
}

// ---------------- layer-1 SpMM: wave per row, 8 edge-groups x 8 dim-octs ----------------
// Each lane gathers uint4 (8 bf16 dims); 8 lanes cover a row; one gather instruction
// serves 8 edges -> half the VMEM instructions of the 16-lane/uint2 layout.

__global__ void spmm1_k(const unsigned short* __restrict__ emb16,
                        const int* __restrict__ rowStart, const int* __restrict__ rowLen,
                        const int2* __restrict__ pairs,
                        int n_total, unsigned short* __restrict__ e1) {
    int wave = (blockIdx.x * blockDim.x + threadIdx.x) >> 6;
    int lane = threadIdx.x & 63;
    if (wave >= n_total) return;
    int eg = lane >> 3, dp = lane & 7;   // 8 edge groups, 8 dim-octs
    unsigned off0 = dp * 16u;            // byte offset of this lane's 8 bf16 dims
    const char* base = (const char*)emb16;
    int len = rowLen[wave];
    const int2* pp = pairs + rowStart[wave];
    float4 aA0 = {0.f, 0.f, 0.f, 0.f}, aA1 = {0.f, 0.f, 0.f, 0.f};
    float4 aB0 = {0.f, 0.f, 0.f, 0.f}, aB1 = {0.f, 0.f, 0.f, 0.f};
    int k = 0;
    for (; k + 16 <= len; k += 16) {
        int4 q = *(const int4*)(pp + k + 2 * eg);   // edges k+2eg, k+2eg+1
        uint4 g0 = *(const uint4*)(base + ((unsigned)q.x + off0));
        uint4 g1 = *(const uint4*)(base + ((unsigned)q.z + off0));
        float v0 = __int_as_float(q.y), v1 = __int_as_float(q.w);
        float4 x0 = bf2f4(g0.x, g0.y), x1 = bf2f4(g0.z, g0.w);
        float4 y0 = bf2f4(g1.x, g1.y), y1 = bf2f4(g1.z, g1.w);
        aA0.x += v0 * x0.x; aA0.y += v0 * x0.y; aA0.z += v0 * x0.z; aA0.w += v0 * x0.w;
        aA1.x += v0 * x1.x; aA1.y += v0 * x1.y; aA1.z += v0 * x1.z; aA1.w += v0 * x1.w;
        aB0.x += v1 * y0.x; aB0.y += v1 * y0.y; aB0.z += v1 * y0.z; aB0.w += v1 * y0.w;
        aB1.x += v1 * y1.x; aB1.y += v1 * y1.y; aB1.z += v1 * y1.z; aB1.w += v1 * y1.w;
    }
    if (k < len) {  // one trailing 8-block: edge k+eg (one per group)
        int2 p = pp[k + eg];
        uint4 g0 = *(const uint4*)(base + ((unsigned)p.x + off0));
        float v0 = __int_as_float(p.y);
        float4 x0 = bf2f4(g0.x, g0.y), x1 = bf2f4(g0.z, g0.w);
        aA0.x += v0 * x0.x; aA0.y += v0 * x0.y; aA0.z += v0 * x0.z; aA0.w += v0 * x0.w;
        aA1.x += v0 * x1.x; aA1.y += v0 * x1.y; aA1.z += v0 * x1.z; aA1.w += v0 * x1.w;
    }
    float4 s0, s1;
    s0.x = aA0.x + aB0.x; s0.y = aA0.y + aB0.y; s0.z = aA0.z + aB0.z; s0.w = aA0.w + aB0.w;
    s1.x = aA1.x + aB1.x; s1.y = aA1.y + aB1.y; s1.z = aA1.z + aB1.z; s1.w = aA1.w + aB1.w;
#pragma unroll
    for (int m = 8; m <= 32; m <<= 1) {
        s0.x += __shfl_xor(s0.x, m); s0.y += __shfl_xor(s0.y, m);
        s0.z += __shfl_xor(s0.z, m); s0.w += __shfl_xor(s0.w, m);
        s1.x += __shfl_xor(s1.x, m); s1.y += __shfl_xor(s1.y, m);
        s1.z += __shfl_xor(s1.z, m); s1.w += __shfl_xor(s1.w, m);
    }
    if (eg == 0) {
        uint4 o;
        o.x = (unsigned)f2bf(s0.x) | ((unsigned)f2bf(s0.y) << 16);
        o.y = (unsigned)f2bf(s0.z) | ((unsigned)f2bf(s0.w) << 16);
        o.z = (unsigned)f2bf(s1.x) | ((unsigned)f2bf(s1.y) << 16);
        o.w = (unsigned)f2bf(s1.z) | ((unsigned)f2bf(s1.w) << 16);
        *(uint4*)(e1 + (size_t)wave * DIM + dp * 8) = o;
    }
}

// ---------------- fused layer-2 + gather + dot epilogue (r7 form) ----------------

__global__ void final_k(const float* __restrict__ emb_user, const float* __restrict__ emb_item,
                        int n_user, const unsigned short* __restrict__ e1,
                        const int* __restrict__ rowStart, const int* __restrict__ rowLen,
                        const int2* __restrict__ pairs,
                        const int* __restrict__ u_nodes, const int* __restrict__ p_nodes,
                        const int* __restrict__ n_nodes, int B, float* __restrict__ out) {
    int wave = (blockIdx.x * blockDim.x + threadIdx.x) >> 6;
    int lane = threadIdx.x & 63;
    if (wave >= B) return;
    int eg = lane >> 4, dp = lane & 15;
    unsigned off0 = dp * 8u;
    const char* base = (const char*)e1;
    int nid[3] = {u_nodes[wave], p_nodes[wave], n_nodes[wave]};
    float4 l[3];
#pragma unroll
    for (int j = 0; j < 3; j++) {
        int r = nid[j];
        const float* base0 = (r < n_user) ? (emb_user + (size_t)r * DIM)
                                          : (emb_item + (size_t)(r - n_user) * DIM);
        float4 acc = *(const float4*)(base0 + dp * 4);                       // layer0 f32
        float4 t1 = bf2f4(*(const uint2*)(e1 + (size_t)r * DIM + dp * 4));   // layer1
        acc.x += t1.x; acc.y += t1.y; acc.z += t1.z; acc.w += t1.w;
        int len = rowLen[r];
        const int2* pp = pairs + rowStart[r];
        float4 a0 = {0.f, 0.f, 0.f, 0.f}, a1 = {0.f, 0.f, 0.f, 0.f};
        float4 a2 = {0.f, 0.f, 0.f, 0.f}, a3 = {0.f, 0.f, 0.f, 0.f};
        int k = 0;
        for (; k + 16 <= len; k += 16) {
            int4 q0 = *(const int4*)(pp + k + 2 * eg);
            int4 q1 = *(const int4*)(pp + k + 8 + 2 * eg);
            uint2 g0 = *(const uint2*)(base + ((unsigned)q0.x + off0));
            uint2 g1 = *(const uint2*)(base + ((unsigned)q0.z + off0));
            uint2 g2 = *(const uint2*)(base + ((unsigned)q1.x + off0));
            uint2 g3 = *(const uint2*)(base + ((unsigned)q1.z + off0));
            float v0 = __int_as_float(q0.y), v1 = __int_as_float(q0.w);
            float v2 = __int_as_float(q1.y), v3 = __int_as_float(q1.w);
            float4 x0 = bf2f4(g0), x1 = bf2f4(g1), x2 = bf2f4(g2), x3 = bf2f4(g3);
            a0.x += v0 * x0.x; a0.y += v0 * x0.y; a0.z += v0 * x0.z; a0.w += v0 * x0.w;
            a1.x += v1 * x1.x; a1.y += v1 * x1.y; a1.z += v1 * x1.z; a1.w += v1 * x1.w;
            a2.x += v2 * x2.x; a2.y += v2 * x2.y; a2.z += v2 * x2.z; a2.w += v2 * x2.w;
            a3.x += v3 * x3.x; a3.y += v3 * x3.y; a3.z += v3 * x3.z; a3.w += v3 * x3.w;
        }
        for (; k < len; k += 8) {
            int4 q0 = *(const int4*)(pp + k + 2 * eg);
            uint2 g0 = *(const uint2*)(base + ((unsigned)q0.x + off0));
            uint2 g1 = *(const uint2*)(base + ((unsigned)q0.z + off0));
            float v0 = __int_as_float(q0.y), v1 = __int_as_float(q0.w);
            float4 x0 = bf2f4(g0), x1 = bf2f4(g1);
            a0.x += v0 * x0.x; a0.y += v0 * x0.y; a0.z += v0 * x0.z; a0.w += v0 * x0.w;
            a1.x += v1 * x1.x; a1.y += v1 * x1.y; a1.z += v1 * x1.z; a1.w += v1 * x1.w;
        }
        float4 s;
        s.x = (a0.x + a1.x) + (a2.x + a3.x);
        s.y = (a0.y + a1.y) + (a2.y + a3.y);
        s.z = (a0.z + a1.z) + (a2.z + a3.z);
        s.w = (a0.w + a1.w) + (a2.w + a3.w);
        s.x += __shfl_xor(s.x, 16); s.y += __shfl_xor(s.y, 16);
        s.z += __shfl_xor(s.z, 16); s.w += __shfl_xor(s.w, 16);
        s.x += __shfl_xor(s.x, 32); s.y += __shfl_xor(s.y, 32);
        s.z += __shfl_xor(s.z, 32); s.w += __shfl_xor(s.w, 32);
        l[j].x = (acc.x + s.x) * (1.0f / 3.0f);
        l[j].y = (acc.y + s.y) * (1.0f / 3.0f);
        l[j].z = (acc.z + s.z) * (1.0f / 3.0f);
        l[j].w = (acc.w + s.w) * (1.0f / 3.0f);
    }
    float ps = l[0].x * l[1].x + l[0].y * l[1].y + l[0].z * l[1].z + l[0].w * l[1].w;
    float ns = l[0].x * l[2].x + l[0].y * l[2].y + l[0].z * l[2].z + l[0].w * l[2].w;
    ps += __shfl_xor(ps, 1); ns += __shfl_xor(ns, 1);
    ps += __shfl_xor(ps, 2); ns += __shfl_xor(ns, 2);
    ps += __shfl_xor(ps, 4); ns += __shfl_xor(ns, 4);
    ps += __shfl_xor(ps, 8); ns += __shfl_xor(ns, 8);
    if (lane == 0) {
        out[wave] = ps;
        out[B + wave] = ns;
    }
}

extern "C" void kernel_launch(void* const* d_in, const int* in_sizes, int n_in,
                              void* d_out, int out_size, void* d_ws, size_t ws_size,
                              hipStream_t stream) {
    const float* emb_user = (const float*)d_in[0];
    const float* emb_item = (const float*)d_in[1];
    const float* gvals    = (const float*)d_in[2];
    const int*   grow     = (const int*)d_in[3];
    const int*   gcol     = (const int*)d_in[4];
    const int*   unodes   = (const int*)d_in[5];
    const int*   pnodes   = (const int*)d_in[6];
    const int*   nnodes   = (const int*)d_in[7];
    float* out = (float*)d_out;

    int n_user = in_sizes[0] / DIM;
    int n_item = in_sizes[1] / DIM;
    int N = n_user + n_item;
    int E = in_sizes[2];
    int B = in_sizes[5];
    int NB = (N + RPB - 1) >> BSHIFT;
    int NBLK = (E + CHUNK - 1) / CHUNK;
    int padSlop = RPB * PADMASK;

    char* ws = (char*)d_ws;
    size_t off = 0;
    auto alloc = [&](size_t bytes) -> void* {
        void* p = ws + off;
        off = (off + bytes + 255) & ~(size_t)255;
        return p;
    };
    size_t embBytes = (size_t)N * DIM * 2;
    size_t countsBytes = (size_t)NBLK * NB * 4;
    size_t regionBBytes = (size_t)E * 8 > embBytes ? (size_t)E * 8 : embBytes;
    size_t regionABytes = countsBytes > embBytes ? countsBytes : embBytes;
    size_t pairsBytes = ((size_t)E + (size_t)NB * padSlop) * 8;

    int*  rowStart    = (int*)alloc((size_t)N * 4);
    int*  rowLen      = (int*)alloc((size_t)N * 4);
    int*  bucketTotal = (int*)alloc((size_t)MAXNB * 4);
    int*  bucketStart = (int*)alloc((size_t)(MAXNB + 1) * 4);
    int2* pairs       = (int2*)alloc(pairsBytes);
    char* regionB = (char*)alloc(regionBBytes);
    int2*           bdata = (int2*)regionB;   // dead after p2
    unsigned short* emb16 = (unsigned short*)regionB;
    char* regionA = (char*)alloc(regionABytes);
    int*            counts = (int*)regionA;   // dead after p1c
    unsigned short* e1     = (unsigned short*)regionA;
    (void)n_in; (void)out_size; (void)ws_size;

    // CSR build via two-level counting sort (no global atomics)
    p1a_hist<<<NBLK, 256, 0, stream>>>(grow, E, NB, counts);
    p1b_scan<<<NB, 256, 0, stream>>>(counts, NBLK, NB, bucketTotal);
    p_scan_tot<<<1, 256, 0, stream>>>(bucketTotal, NB, bucketStart);
    p1c_scatter<<<NBLK, 256, 0, stream>>>(grow, gcol, gvals, E, NB, counts, bucketStart, bdata);
    p2_group<<<NB, 256, 0, stream>>>(bdata, bucketStart, NB, N, padSlop,
                                     rowStart, rowLen, pairs);

    // bf16 pack of embeddings (after p2: emb16 overlays dead bdata)
    conv2_k<<<2048, 256, 0, stream>>>(emb_user, emb_item, n_user * DIM, N * DIM, emb16);

    // layer-1 SpMM over all rows (e1 overlays dead counts)
    spmm1_k<<<(N + 3) / 4, 256, 0, stream>>>(emb16, rowStart, rowLen, pairs, N, e1);
    // fused layer-2 + gather + dots
    final_k<<<(B + 3) / 4, 256, 0, stream>>>(emb_user, emb_item, n_user, e1,
                                             rowStart, rowLen, pairs,
                                             unodes, pnodes, nnodes, B, out);
}